// Round 12
// baseline (795.061 us; speedup 1.0000x reference)
//
#include <hip/hip_runtime.h>
#include <cmath>

// EMD approxmatch, B=16, N=M=2048, f32. Multi-launch (kernel boundary = sync),
// factorized per-level update (nothing [N,M]-shaped):
//   COL j: A[m] = sum_n e_j*ratioL[n]; rr = satr*min(satr/(satr*A+eps),1);
//          satr = max(satr - rr*A, 0)
//   ROW j: s1 = sum_m e_j*rr; s2 = sum_m e_j*rr*dist; satl=max(satl-rl*s1,0);
//          cost += rl*s2; fused next ratioL via e2 = exp2(c_{j+1}*d2),
//          e_j = e2^4 exactly (levels scale by 4).
// Round 12: 512-thread blocks, grid=1024=256CUx4, 40KB LDS -> 32 waves/CU
// (was 29% measured occupancy with 256T), satr staged in LDS (no inner-loop
// VMEM), single residency round. Inner loop = proven round-9 body.
// Underflow skip (-149 = exact f32 zero; looser cutoffs are INVALID because
// the reference's per-row normalization allocates full supply even for tiny
// exp values) kept for ROW j<=2 / COL j<=3 / row_start.

#define NB 16
#define NPTS 2048
#define NH 1024                 // v2f pair count
#define TPB 512
#define EPS_F 1e-9f
#define UFLOW (-149.0f)         // exp2 exact-zero threshold (f32)

typedef float v2f __attribute__((ext_vector_type(2)));

__device__ __forceinline__ float fast_exp2(float x) { return __builtin_amdgcn_exp2f(x); }
__device__ __forceinline__ float fast_sqrt(float x) { return __builtin_amdgcn_sqrtf(x); }
__device__ __forceinline__ v2f v2(float s) { v2f r; r.x = s; r.y = s; return r; }
__device__ __forceinline__ v2f vfma(v2f a, v2f b, v2f c) { return __builtin_elementwise_fma(a, b, c); }
__device__ __forceinline__ v2f vmax0(v2f a) { return __builtin_elementwise_max(a, v2(0.0f)); }
__device__ __forceinline__ v2f vmin2(v2f a, v2f b) { return __builtin_elementwise_min(a, b); }
__device__ __forceinline__ v2f vmax2(v2f a, v2f b) { return __builtin_elementwise_max(a, b); }
__device__ __forceinline__ v2f vexp2(v2f a) { v2f r; r.x = fast_exp2(a.x); r.y = fast_exp2(a.y); return r; }
__device__ __forceinline__ v2f vsqrt(v2f a) { v2f r; r.x = fast_sqrt(a.x); r.y = fast_sqrt(a.y); return r; }

// 4-way select without runtime indexing (3 cndmask)
__device__ __forceinline__ float sel4(float a0, float a1, float a2, float a3, int k) {
    float x = a0;
    x = (k == 1) ? a1 : x; x = (k == 2) ? a2 : x; x = (k == 3) ? a3 : x;
    return x;
}
#define SEL4(A, k) sel4(A[0], A[1], A[2], A[3], k)

// staging: SoA v2f tiles, thread t owns v2f-indices t, t+512 (conflict-free)
#define STAGE_CW(Cb, Wb)                                                   \
    for (int i = tid; i < NH; i += TPB) {                                  \
        const float2* c2 = (const float2*)(Cb) + 3 * i;                    \
        float2 A_ = c2[0], B_ = c2[1], C_ = c2[2];                         \
        Sx[i] = (v2f){A_.x, B_.y};                                         \
        Sy[i] = (v2f){A_.y, C_.x};                                         \
        Sz[i] = (v2f){B_.x, C_.y};                                         \
        float2 w_ = *((const float2*)(Wb) + i);                            \
        Sw[i] = (v2f){w_.x, w_.y};                                         \
    }
#define STAGE_C(Cb)                                                        \
    for (int i = tid; i < NH; i += TPB) {                                  \
        const float2* c2 = (const float2*)(Cb) + 3 * i;                    \
        float2 A_ = c2[0], B_ = c2[1], C_ = c2[2];                         \
        Sx[i] = (v2f){A_.x, B_.y};                                         \
        Sy[i] = (v2f){A_.y, C_.x};                                         \
        Sz[i] = (v2f){B_.x, C_.y};                                         \
    }
#define STAGE_N(Nb)                                                        \
    for (int i = tid; i < NH; i += TPB) {                                  \
        float2 w_ = *((const float2*)(Nb) + i);                            \
        Sn[i] = (v2f){w_.x, w_.y};                                         \
    }

// ratioL[n] = 1/(sum_m exp2(c0*d2) + eps)  (satl = satr = 1). Zeroes costAcc.
__global__ __launch_bounds__(TPB, 8) void row_start(const float* __restrict__ pred,
                                                    const float* __restrict__ gt,
                                                    float* __restrict__ ratioL,
                                                    float* __restrict__ costAcc,
                                                    float c0) {
    __shared__ v2f Sx[NH], Sy[NH], Sz[NH];
    const int b = blockIdx.x >> 6;                    // 64 blocks/batch, 32 rows
    const int base = (blockIdx.x & 63) * 32;
    const int tid = threadIdx.x, wave = tid >> 6, lane = tid & 63;
    if (blockIdx.x == 0 && tid == 0) costAcc[0] = 0.0f;
    const float* Gb = gt + (size_t)b * NPTS * 3;
    STAGE_C(Gb);
    __syncthreads();
    const int own0 = base + wave * 4;
    const float* p0 = pred + ((size_t)b * NPTS + own0) * 3;
    float cx[4], cy[4], cz[4], cb[4];                 // c0 folded into dot form
    v2f a[4];
    #pragma unroll
    for (int r = 0; r < 4; ++r) {
        float px = p0[r * 3], py = p0[r * 3 + 1], pz = p0[r * 3 + 2];
        cx[r] = -2.0f * c0 * px; cy[r] = -2.0f * c0 * py; cz[r] = -2.0f * c0 * pz;
        cb[r] = c0 * (px * px + py * py + pz * pz);
        a[r] = v2(0.0f);
    }
    for (int i = lane; i < NH; i += 64) {
        v2f gx = Sx[i], gy = Sy[i], gz = Sz[i];
        v2f cg2 = vfma(gx, gx, vfma(gy, gy, gz * gz)) * v2(c0);
        v2f arg[4];
        #pragma unroll
        for (int r = 0; r < 4; ++r)
            arg[r] = vmin2(vfma(v2(cx[r]), gx, vfma(v2(cy[r]), gy,
                           vfma(v2(cz[r]), gz, cg2 + v2(cb[r])))), v2(0.0f));
        v2f m2 = vmax2(vmax2(arg[0], arg[1]), vmax2(arg[2], arg[3]));
        if (__any(fmaxf(m2.x, m2.y) > UFLOW)) {
            #pragma unroll
            for (int r = 0; r < 4; ++r) a[r] += vexp2(arg[r]);
        }
    }
    float as[4];
    #pragma unroll
    for (int r = 0; r < 4; ++r) as[r] = a[r].x + a[r].y;
    #pragma unroll
    for (int o = 1; o < 64; o <<= 1) {
        #pragma unroll
        for (int r = 0; r < 4; ++r) as[r] += __shfl_xor(as[r], o);
    }
    if (lane < 4)
        ratioL[b * NPTS + own0 + lane] = 1.0f / (SEL4(as, lane) + EPS_F);
}

// A[m] = sum_n exp2(c*d2)*ratioL[n]; rr = satr*min(satr/(satr*A+eps),1);
// satr = max(satr - rr*A, 0).  FIRST: satr = 1.  SKIP: vote per iteration.
template <bool FIRST, bool SKIP>
__global__ __launch_bounds__(TPB, 8) void col_pass(const float* __restrict__ pred,
                                                   const float* __restrict__ gt,
                                                   const float* __restrict__ ratioL,
                                                   float* __restrict__ ratioR,
                                                   float* __restrict__ satr,
                                                   float c) {
    __shared__ v2f Sx[NH], Sy[NH], Sz[NH], Sw[NH];
    const int b = blockIdx.x >> 6;
    const int base = (blockIdx.x & 63) * 32;
    const int tid = threadIdx.x, wave = tid >> 6, lane = tid & 63;
    const float* Pb = pred + (size_t)b * NPTS * 3;
    STAGE_CW(Pb, ratioL + b * NPTS);
    __syncthreads();
    const int own0 = base + wave * 4;
    const float* g0 = gt + ((size_t)b * NPTS + own0) * 3;
    float cx[4], cy[4], cz[4], cb[4];
    v2f a[4];
    #pragma unroll
    for (int r = 0; r < 4; ++r) {
        float gx = g0[r * 3], gy = g0[r * 3 + 1], gz = g0[r * 3 + 2];
        cx[r] = -2.0f * c * gx; cy[r] = -2.0f * c * gy; cz[r] = -2.0f * c * gz;
        cb[r] = c * (gx * gx + gy * gy + gz * gz);
        a[r] = v2(0.0f);
    }
    for (int i = lane; i < NH; i += 64) {
        v2f px = Sx[i], py = Sy[i], pz = Sz[i];
        v2f cp2 = vfma(px, px, vfma(py, py, pz * pz)) * v2(c);
        v2f arg[4];
        #pragma unroll
        for (int r = 0; r < 4; ++r)
            arg[r] = vmin2(vfma(v2(cx[r]), px, vfma(v2(cy[r]), py,
                           vfma(v2(cz[r]), pz, cp2 + v2(cb[r])))), v2(0.0f));
        bool take = true;
        if (SKIP) {
            v2f m2 = vmax2(vmax2(arg[0], arg[1]), vmax2(arg[2], arg[3]));
            take = __any(fmaxf(m2.x, m2.y) > UFLOW);
        }
        if (take) {
            v2f rl = Sw[i];
            #pragma unroll
            for (int r = 0; r < 4; ++r) a[r] = vfma(vexp2(arg[r]), rl, a[r]);
        }
    }
    float as[4];
    #pragma unroll
    for (int r = 0; r < 4; ++r) as[r] = a[r].x + a[r].y;
    #pragma unroll
    for (int o = 1; o < 64; o <<= 1) {
        #pragma unroll
        for (int r = 0; r < 4; ++r) as[r] += __shfl_xor(as[r], o);
    }
    if (lane < 4) {
        const int idx = b * NPTS + own0 + lane;
        const float A = SEL4(as, lane);
        const float sr = FIRST ? 1.0f : satr[idx];
        const float ss = fmaf(sr, A, EPS_F);
        const float rr = sr * fminf(sr / ss, 1.0f);
        ratioR[idx] = rr;
        satr[idx] = fmaxf(fmaf(-rr, A, sr), 0.0f);
    }
}

// Last level (exp == 1): A is column-independent = sum_n ratioL[n].
__global__ __launch_bounds__(256) void col_last(const float* __restrict__ ratioL,
                                                float* __restrict__ ratioR,
                                                const float* __restrict__ satr) {
    __shared__ float part[256];
    const int b = blockIdx.x;
    float acc = 0.0f;
    for (int i = threadIdx.x; i < NPTS; i += 256) acc += ratioL[b * NPTS + i];
    part[threadIdx.x] = acc;
    __syncthreads();
    for (int s = 128; s > 0; s >>= 1) {
        if (threadIdx.x < s) part[threadIdx.x] += part[threadIdx.x + s];
        __syncthreads();
    }
    const float sumRL = part[0];
    for (int m = threadIdx.x; m < NPTS; m += 256) {
        const int idx = b * NPTS + m;
        const float sr = satr[idx];
        const float ss = fmaf(sr, sumRL, EPS_F);
        ratioR[idx] = sr * fminf(sr / ss, 1.0f);
    }
}

// MODE 0 (j<=8): e2 = exp2(cq*d2), e1 = (e2^2)^2; an += e2*satr  (cq = c/4)
// MODE 1 (j==9): e1 = exp2(c*d2); an_all = sum satr
// MODE 2 (j==10): e1 = 1; cost only.   FIRST: satl = 1.  SKIP: per-iter vote.
template <int MODE, bool FIRST, bool SKIP>
__global__ __launch_bounds__(TPB, 8) void row_finish(const float* __restrict__ pred,
                                                     const float* __restrict__ gt,
                                                     float* __restrict__ satl,
                                                     float* __restrict__ ratioL,
                                                     const float* __restrict__ ratioR,
                                                     const float* __restrict__ satr,
                                                     float* __restrict__ costAcc,
                                                     float c1, float cq) {
    __shared__ v2f Sx[NH], Sy[NH], Sz[NH], Sw[NH], Sn[NH];  // 40960 B = 160KiB/4
    const int b = blockIdx.x >> 6;
    const int base = (blockIdx.x & 63) * 32;
    const int tid = threadIdx.x, wave = tid >> 6, lane = tid & 63;
    const float* Gb = gt + (size_t)b * NPTS * 3;
    STAGE_CW(Gb, ratioR + b * NPTS);
    if (MODE <= 1) STAGE_N(satr + b * NPTS);
    __syncthreads();
    const int own0 = base + wave * 4;
    const float* p0 = pred + ((size_t)b * NPTS + own0) * 3;
    const float thr = (MODE == 0) ? (UFLOW / cq) : 0.0f;    // cq<0 -> thr>0
    float nx[4], ny[4], nz[4], p2[4];
    v2f s1[4], s2[4], an[4], anall = v2(0.0f);
    #pragma unroll
    for (int r = 0; r < 4; ++r) {
        float px = p0[r * 3], py = p0[r * 3 + 1], pz = p0[r * 3 + 2];
        nx[r] = -2.0f * px; ny[r] = -2.0f * py; nz[r] = -2.0f * pz;
        p2[r] = px * px + py * py + pz * pz;
        s1[r] = v2(0.0f); s2[r] = v2(0.0f); an[r] = v2(0.0f);
    }
    for (int i = lane; i < NH; i += 64) {
        v2f gx = Sx[i], gy = Sy[i], gz = Sz[i];
        v2f g2 = vfma(gx, gx, vfma(gy, gy, gz * gz));
        v2f d2a[4];
        #pragma unroll
        for (int r = 0; r < 4; ++r)
            d2a[r] = vmax0(vfma(v2(nx[r]), gx, vfma(v2(ny[r]), gy,
                           vfma(v2(nz[r]), gz, g2 + v2(p2[r])))));
        if (MODE == 0) {
            bool take = true;
            if (SKIP) {
                v2f mn = vmin2(vmin2(d2a[0], d2a[1]), vmin2(d2a[2], d2a[3]));
                take = __any(fminf(mn.x, mn.y) < thr);
            }
            if (take) {
                v2f rr = Sw[i];
                v2f nr = Sn[i];
                #pragma unroll
                for (int r = 0; r < 4; ++r) {
                    v2f e2 = vexp2(d2a[r] * v2(cq));
                    v2f e22 = e2 * e2;
                    an[r] = vfma(e2, nr, an[r]);
                    v2f t_ = (e22 * e22) * rr;
                    s1[r] += t_;
                    s2[r] = vfma(t_, vsqrt(d2a[r]), s2[r]);
                }
            }
        } else if (MODE == 1) {
            v2f rr = Sw[i];
            anall += Sn[i];
            #pragma unroll
            for (int r = 0; r < 4; ++r) {
                v2f t_ = vexp2(d2a[r] * v2(c1)) * rr;
                s1[r] += t_;
                s2[r] = vfma(t_, vsqrt(d2a[r]), s2[r]);
            }
        } else {
            v2f rr = Sw[i];
            #pragma unroll
            for (int r = 0; r < 4; ++r)
                s2[r] = vfma(rr, vsqrt(d2a[r]), s2[r]);
        }
    }
    float S1[4], S2[4], AN[4], ana = anall.x + anall.y;
    #pragma unroll
    for (int r = 0; r < 4; ++r) {
        S1[r] = s1[r].x + s1[r].y;
        S2[r] = s2[r].x + s2[r].y;
        AN[r] = an[r].x + an[r].y;
    }
    #pragma unroll
    for (int o = 1; o < 64; o <<= 1) {
        #pragma unroll
        for (int r = 0; r < 4; ++r) {
            S2[r] += __shfl_xor(S2[r], o);
            if (MODE <= 1) S1[r] += __shfl_xor(S1[r], o);
            if (MODE == 0) AN[r] += __shfl_xor(AN[r], o);
        }
        if (MODE == 1) ana += __shfl_xor(ana, o);
    }
    float contrib = 0.0f;
    if (lane < 4) {
        const int idx = b * NPTS + own0 + lane;
        const float rl = ratioL[idx];
        contrib = rl * SEL4(S2, lane);
        if (MODE <= 1) {
            const float sl = FIRST ? 1.0f : satl[idx];
            const float nsl = fmaxf(fmaf(-rl, SEL4(S1, lane), sl), 0.0f);
            satl[idx] = nsl;
            const float den = (MODE == 0) ? SEL4(AN, lane) : ana;
            ratioL[idx] = nsl / (den + EPS_F);
        }
    }
    contrib += __shfl_xor(contrib, 1);
    contrib += __shfl_xor(contrib, 2);       // lanes 0..3 hold wave total
    __syncthreads();                          // staging reads done; reuse LDS
    float* scr = (float*)Sx;
    if (lane == 0) scr[wave] = contrib;
    __syncthreads();
    if (tid == 0) {
        float cw = 0.0f;
        #pragma unroll
        for (int w = 0; w < TPB / 64; ++w) cw += scr[w];
        atomicAdd(costAcc, cw);
    }
}

__global__ void finalize(const float* __restrict__ costAcc, float* __restrict__ out) {
    out[0] = costAcc[0] * (1.0f / (float)NPTS);   // radius = 1
}

extern "C" void kernel_launch(void* const* d_in, const int* in_sizes, int n_in,
                              void* d_out, int out_size, void* d_ws, size_t ws_size,
                              hipStream_t stream) {
    const float* pred = (const float*)d_in[0];
    const float* gt   = (const float*)d_in[1];
    float* out = (float*)d_out;

    float* wsf    = (float*)d_ws;
    float* satl   = wsf;
    float* satr   = wsf + NB * NPTS;
    float* ratioL = wsf + 2 * NB * NPTS;
    float* ratioR = wsf + 3 * NB * NPTS;
    float* costAcc = wsf + 4 * NB * NPTS;

    // c[j] = level_j * log2(e); c[j+1] = c[j]/4 exactly for j<=8
    const double LOG2E = 1.4426950408889634;
    float c[11];
    for (int k = 0; k < 10; ++k) c[k] = (float)(-pow(4.0, (double)(8 - k)) * LOG2E);
    c[10] = 0.0f;

    const int blocks = NB * (NPTS / 32);   // 1024 = 256 CU x 4 resident, 1 round

    row_start<<<blocks, TPB, 0, stream>>>(pred, gt, ratioL, costAcc, c[0]);
    // j = 0
    col_pass<true, true><<<blocks, TPB, 0, stream>>>(pred, gt, ratioL, ratioR, satr, c[0]);
    row_finish<0, true, true><<<blocks, TPB, 0, stream>>>(pred, gt, satl, ratioL, ratioR,
                                                          satr, costAcc, c[0], c[1]);
    // j = 1..2: both phases skip-qualified
    for (int j = 1; j <= 2; ++j) {
        col_pass<false, true><<<blocks, TPB, 0, stream>>>(pred, gt, ratioL, ratioR, satr, c[j]);
        row_finish<0, false, true><<<blocks, TPB, 0, stream>>>(pred, gt, satl, ratioL, ratioR,
                                                               satr, costAcc, c[j], c[j + 1]);
    }
    // j = 3: col still skips often; row doesn't
    col_pass<false, true><<<blocks, TPB, 0, stream>>>(pred, gt, ratioL, ratioR, satr, c[3]);
    row_finish<0, false, false><<<blocks, TPB, 0, stream>>>(pred, gt, satl, ratioL, ratioR,
                                                            satr, costAcc, c[3], c[4]);
    // j = 4..8: dense
    for (int j = 4; j <= 8; ++j) {
        col_pass<false, false><<<blocks, TPB, 0, stream>>>(pred, gt, ratioL, ratioR, satr, c[j]);
        row_finish<0, false, false><<<blocks, TPB, 0, stream>>>(pred, gt, satl, ratioL, ratioR,
                                                                satr, costAcc, c[j], c[j + 1]);
    }
    col_pass<false, false><<<blocks, TPB, 0, stream>>>(pred, gt, ratioL, ratioR, satr, c[9]);
    row_finish<1, false, false><<<blocks, TPB, 0, stream>>>(pred, gt, satl, ratioL, ratioR,
                                                            satr, costAcc, c[9], 0.0f);
    col_last<<<NB, 256, 0, stream>>>(ratioL, ratioR, satr);
    row_finish<2, false, false><<<blocks, TPB, 0, stream>>>(pred, gt, satl, ratioL, ratioR,
                                                            satr, costAcc, 0.0f, 0.0f);
    finalize<<<1, 1, 0, stream>>>(costAcc, out);
}

// Round 13
// 629.267 us; speedup vs baseline: 1.2635x; 1.2635x over previous
//
#include <hip/hip_runtime.h>
#include <cmath>

// EMD approxmatch, B=16, N=M=2048, f32. Multi-launch (kernel boundary = sync),
// factorized per-level update (nothing [N,M]-shaped):
//   COL j: A[m] = sum_n e_j*ratioL[n]; rr = satr*min(satr/(satr*A+eps),1);
//          satr = max(satr - rr*A, 0)
//   ROW j: s1 = sum_m e_j*rr; s2 = sum_m e_j*rr*dist; satl=max(satl-rl*s1,0);
//          cost += rl*s2; fused next ratioL via e2 = exp2(c_{j+1}*d2),
//          e_j = e2^4 exactly (levels scale by 4).
// Round 13: SPATIAL SORT (Morton, 8^3 grid) of each batch's points, once, into
// ws copies pp/gg. The pipeline is permutation-invariant; sorting makes the
// underflow-skip granules (4 rows x 128 cols, consecutive in sorted order)
// spatially compact so the existing __any vote skips coherently at j<=5.
// exp2 underflow (-149) is an EXACT f32 zero — bit-safe skip.
// Kernels otherwise identical to the proven 618us round-11 build
// (256T, launch_bounds(256,5), VGPR 44, no spills — round 12's 512T/32VGPR
// spilled 31MB and regressed; occupancy is not the wall).

#define NB 16
#define NPTS 2048
#define NH 1024                 // v2f pair count
#define TPB 256
#define EPS_F 1e-9f
#define UFLOW (-149.0f)         // exp2 exact-zero threshold (f32)

typedef float v2f __attribute__((ext_vector_type(2)));

__device__ __forceinline__ float fast_exp2(float x) { return __builtin_amdgcn_exp2f(x); }
__device__ __forceinline__ float fast_sqrt(float x) { return __builtin_amdgcn_sqrtf(x); }
__device__ __forceinline__ v2f v2(float s) { v2f r; r.x = s; r.y = s; return r; }
__device__ __forceinline__ v2f vfma(v2f a, v2f b, v2f c) { return __builtin_elementwise_fma(a, b, c); }
__device__ __forceinline__ v2f vmax0(v2f a) { return __builtin_elementwise_max(a, v2(0.0f)); }
__device__ __forceinline__ v2f vmin2(v2f a, v2f b) { return __builtin_elementwise_min(a, b); }
__device__ __forceinline__ v2f vmax2(v2f a, v2f b) { return __builtin_elementwise_max(a, b); }
__device__ __forceinline__ v2f vexp2(v2f a) { v2f r; r.x = fast_exp2(a.x); r.y = fast_exp2(a.y); return r; }
__device__ __forceinline__ v2f vsqrt(v2f a) { v2f r; r.x = fast_sqrt(a.x); r.y = fast_sqrt(a.y); return r; }

// 4-way select without runtime indexing (3 cndmask)
__device__ __forceinline__ float sel4(float a0, float a1, float a2, float a3, int k) {
    float x = a0;
    x = (k == 1) ? a1 : x; x = (k == 2) ? a2 : x; x = (k == 3) ? a3 : x;
    return x;
}
#define SEL4(A, k) sel4(A[0], A[1], A[2], A[3], k)

// ---------------- spatial sort (per batch, Morton 9-bit over 8^3 grid) ----
__global__ __launch_bounds__(512) void sort_points(const float* __restrict__ pred,
                                                   const float* __restrict__ gt,
                                                   float* __restrict__ pp,
                                                   float* __restrict__ gg) {
    __shared__ int hist[512];
    __shared__ int keys[NPTS];
    const int b = blockIdx.x;
    const int tid = threadIdx.x;
    for (int pass = 0; pass < 2; ++pass) {
        const float* src = (pass ? gt : pred) + (size_t)b * NPTS * 3;
        float* dst = (pass ? gg : pp) + (size_t)b * NPTS * 3;
        hist[tid] = 0;
        __syncthreads();
        for (int i = tid; i < NPTS; i += 512) {
            float x = src[i * 3], y = src[i * 3 + 1], z = src[i * 3 + 2];
            int cx = min(7, max(0, (int)(x + 4.0f)));
            int cy = min(7, max(0, (int)(y + 4.0f)));
            int cz = min(7, max(0, (int)(z + 4.0f)));
            int key = 0;
            #pragma unroll
            for (int k = 0; k < 3; ++k) {
                key |= ((cx >> k) & 1) << (3 * k + 0);
                key |= ((cy >> k) & 1) << (3 * k + 1);
                key |= ((cz >> k) & 1) << (3 * k + 2);
            }
            keys[i] = key;
            atomicAdd(&hist[key], 1);
        }
        __syncthreads();
        int cnt = hist[tid];
        for (int off = 1; off < 512; off <<= 1) {       // inclusive scan
            int t = (tid >= off) ? hist[tid - off] : 0;
            __syncthreads();
            hist[tid] += t;
            __syncthreads();
        }
        hist[tid] -= cnt;                               // exclusive start
        __syncthreads();
        for (int i = tid; i < NPTS; i += 512) {
            int d = atomicAdd(&hist[keys[i]], 1);
            dst[d * 3 + 0] = src[i * 3 + 0];
            dst[d * 3 + 1] = src[i * 3 + 1];
            dst[d * 3 + 2] = src[i * 3 + 2];
        }
        __syncthreads();
    }
}

// staging: SoA v2f tiles, thread t owns v2f-indices t, t+256 (conflict-free)
#define STAGE_CW(Cb, Wb)                                                   \
    for (int i = tid; i < NH; i += TPB) {                                  \
        const float2* c2 = (const float2*)(Cb) + 3 * i;                    \
        float2 A_ = c2[0], B_ = c2[1], C_ = c2[2];                         \
        Sx[i] = (v2f){A_.x, B_.y};                                         \
        Sy[i] = (v2f){A_.y, C_.x};                                         \
        Sz[i] = (v2f){B_.x, C_.y};                                         \
        float2 w_ = *((const float2*)(Wb) + i);                            \
        Sw[i] = (v2f){w_.x, w_.y};                                         \
    }
#define STAGE_C(Cb)                                                        \
    for (int i = tid; i < NH; i += TPB) {                                  \
        const float2* c2 = (const float2*)(Cb) + 3 * i;                    \
        float2 A_ = c2[0], B_ = c2[1], C_ = c2[2];                         \
        Sx[i] = (v2f){A_.x, B_.y};                                         \
        Sy[i] = (v2f){A_.y, C_.x};                                         \
        Sz[i] = (v2f){B_.x, C_.y};                                         \
    }

// ratioL[n] = 1/(sum_m exp2(c0*d2) + eps)  (satl = satr = 1). Zeroes costAcc.
__global__ __launch_bounds__(TPB, 5) void row_start(const float* __restrict__ pred,
                                                    const float* __restrict__ gt,
                                                    float* __restrict__ ratioL,
                                                    float* __restrict__ costAcc,
                                                    float c0) {
    __shared__ v2f Sx[NH], Sy[NH], Sz[NH];
    const int b = blockIdx.x >> 7;                    // 128 blocks/batch, 16 rows
    const int base = (blockIdx.x & 127) * 16;
    const int tid = threadIdx.x, wave = tid >> 6, lane = tid & 63;
    if (blockIdx.x == 0 && tid == 0) costAcc[0] = 0.0f;
    const float* Gb = gt + (size_t)b * NPTS * 3;
    STAGE_C(Gb);
    __syncthreads();
    const int own0 = base + wave * 4;
    const float* p0 = pred + ((size_t)b * NPTS + own0) * 3;
    float cx[4], cy[4], cz[4], cb[4];                 // c0 folded into dot form
    v2f a[4];
    #pragma unroll
    for (int r = 0; r < 4; ++r) {
        float px = p0[r * 3], py = p0[r * 3 + 1], pz = p0[r * 3 + 2];
        cx[r] = -2.0f * c0 * px; cy[r] = -2.0f * c0 * py; cz[r] = -2.0f * c0 * pz;
        cb[r] = c0 * (px * px + py * py + pz * pz);
        a[r] = v2(0.0f);
    }
    for (int i = lane; i < NH; i += 64) {
        v2f gx = Sx[i], gy = Sy[i], gz = Sz[i];
        v2f cg2 = vfma(gx, gx, vfma(gy, gy, gz * gz)) * v2(c0);
        v2f arg[4];
        #pragma unroll
        for (int r = 0; r < 4; ++r)
            arg[r] = vmin2(vfma(v2(cx[r]), gx, vfma(v2(cy[r]), gy,
                           vfma(v2(cz[r]), gz, cg2 + v2(cb[r])))), v2(0.0f));
        v2f m2 = vmax2(vmax2(arg[0], arg[1]), vmax2(arg[2], arg[3]));
        if (__any(fmaxf(m2.x, m2.y) > UFLOW)) {
            #pragma unroll
            for (int r = 0; r < 4; ++r) a[r] += vexp2(arg[r]);
        }
    }
    float as[4];
    #pragma unroll
    for (int r = 0; r < 4; ++r) as[r] = a[r].x + a[r].y;
    #pragma unroll
    for (int o = 1; o < 64; o <<= 1) {
        #pragma unroll
        for (int r = 0; r < 4; ++r) as[r] += __shfl_xor(as[r], o);
    }
    if (lane < 4)
        ratioL[b * NPTS + own0 + lane] = 1.0f / (SEL4(as, lane) + EPS_F);
}

// A[m] = sum_n exp2(c*d2)*ratioL[n]; rr = satr*min(satr/(satr*A+eps),1);
// satr = max(satr - rr*A, 0).  FIRST: satr = 1.  SKIP: vote per iteration.
template <bool FIRST, bool SKIP>
__global__ __launch_bounds__(TPB, 5) void col_pass(const float* __restrict__ pred,
                                                   const float* __restrict__ gt,
                                                   const float* __restrict__ ratioL,
                                                   float* __restrict__ ratioR,
                                                   float* __restrict__ satr,
                                                   float c) {
    __shared__ v2f Sx[NH], Sy[NH], Sz[NH], Sw[NH];
    const int b = blockIdx.x >> 7;
    const int base = (blockIdx.x & 127) * 16;
    const int tid = threadIdx.x, wave = tid >> 6, lane = tid & 63;
    const float* Pb = pred + (size_t)b * NPTS * 3;
    STAGE_CW(Pb, ratioL + b * NPTS);
    __syncthreads();
    const int own0 = base + wave * 4;
    const float* g0 = gt + ((size_t)b * NPTS + own0) * 3;
    float cx[4], cy[4], cz[4], cb[4];
    v2f a[4];
    #pragma unroll
    for (int r = 0; r < 4; ++r) {
        float gx = g0[r * 3], gy = g0[r * 3 + 1], gz = g0[r * 3 + 2];
        cx[r] = -2.0f * c * gx; cy[r] = -2.0f * c * gy; cz[r] = -2.0f * c * gz;
        cb[r] = c * (gx * gx + gy * gy + gz * gz);
        a[r] = v2(0.0f);
    }
    for (int i = lane; i < NH; i += 64) {
        v2f px = Sx[i], py = Sy[i], pz = Sz[i];
        v2f cp2 = vfma(px, px, vfma(py, py, pz * pz)) * v2(c);
        v2f arg[4];
        #pragma unroll
        for (int r = 0; r < 4; ++r)
            arg[r] = vmin2(vfma(v2(cx[r]), px, vfma(v2(cy[r]), py,
                           vfma(v2(cz[r]), pz, cp2 + v2(cb[r])))), v2(0.0f));
        bool take = true;
        if (SKIP) {
            v2f m2 = vmax2(vmax2(arg[0], arg[1]), vmax2(arg[2], arg[3]));
            take = __any(fmaxf(m2.x, m2.y) > UFLOW);
        }
        if (take) {
            v2f rl = Sw[i];
            #pragma unroll
            for (int r = 0; r < 4; ++r) a[r] = vfma(vexp2(arg[r]), rl, a[r]);
        }
    }
    float as[4];
    #pragma unroll
    for (int r = 0; r < 4; ++r) as[r] = a[r].x + a[r].y;
    #pragma unroll
    for (int o = 1; o < 64; o <<= 1) {
        #pragma unroll
        for (int r = 0; r < 4; ++r) as[r] += __shfl_xor(as[r], o);
    }
    if (lane < 4) {
        const int idx = b * NPTS + own0 + lane;
        const float A = SEL4(as, lane);
        const float sr = FIRST ? 1.0f : satr[idx];
        const float ss = fmaf(sr, A, EPS_F);
        const float rr = sr * fminf(sr / ss, 1.0f);
        ratioR[idx] = rr;
        satr[idx] = fmaxf(fmaf(-rr, A, sr), 0.0f);
    }
}

// Last level (exp == 1): A is column-independent = sum_n ratioL[n].
__global__ __launch_bounds__(256) void col_last(const float* __restrict__ ratioL,
                                                float* __restrict__ ratioR,
                                                const float* __restrict__ satr) {
    __shared__ float part[256];
    const int b = blockIdx.x;
    float acc = 0.0f;
    for (int i = threadIdx.x; i < NPTS; i += 256) acc += ratioL[b * NPTS + i];
    part[threadIdx.x] = acc;
    __syncthreads();
    for (int s = 128; s > 0; s >>= 1) {
        if (threadIdx.x < s) part[threadIdx.x] += part[threadIdx.x + s];
        __syncthreads();
    }
    const float sumRL = part[0];
    for (int m = threadIdx.x; m < NPTS; m += 256) {
        const int idx = b * NPTS + m;
        const float sr = satr[idx];
        const float ss = fmaf(sr, sumRL, EPS_F);
        ratioR[idx] = sr * fminf(sr / ss, 1.0f);
    }
}

// MODE 0 (j<=8): e2 = exp2(cq*d2), e1 = (e2^2)^2; an += e2*satr  (cq = c/4)
// MODE 1 (j==9): e1 = exp2(c*d2); an_all = sum satr
// MODE 2 (j==10): e1 = 1; cost only.   FIRST: satl = 1.  SKIP: per-iter vote.
template <int MODE, bool FIRST, bool SKIP>
__global__ __launch_bounds__(TPB, 5) void row_finish(const float* __restrict__ pred,
                                                     const float* __restrict__ gt,
                                                     float* __restrict__ satl,
                                                     float* __restrict__ ratioL,
                                                     const float* __restrict__ ratioR,
                                                     const float* __restrict__ satr,
                                                     float* __restrict__ costAcc,
                                                     float c1, float cq) {
    __shared__ v2f Sx[NH], Sy[NH], Sz[NH], Sw[NH];   // 32768 B
    const int b = blockIdx.x >> 7;
    const int base = (blockIdx.x & 127) * 16;
    const int tid = threadIdx.x, wave = tid >> 6, lane = tid & 63;
    const float* Gb = gt + (size_t)b * NPTS * 3;
    STAGE_CW(Gb, ratioR + b * NPTS);
    __syncthreads();
    const int own0 = base + wave * 4;
    const float* p0 = pred + ((size_t)b * NPTS + own0) * 3;
    const float2* nrp = (const float2*)(satr + b * NPTS);   // L1/L2-hot
    const float thr = (MODE == 0) ? (UFLOW / cq) : 0.0f;    // cq<0 -> thr>0
    float nx[4], ny[4], nz[4], p2[4];
    v2f s1[4], s2[4], an[4], anall = v2(0.0f);
    #pragma unroll
    for (int r = 0; r < 4; ++r) {
        float px = p0[r * 3], py = p0[r * 3 + 1], pz = p0[r * 3 + 2];
        nx[r] = -2.0f * px; ny[r] = -2.0f * py; nz[r] = -2.0f * pz;
        p2[r] = px * px + py * py + pz * pz;
        s1[r] = v2(0.0f); s2[r] = v2(0.0f); an[r] = v2(0.0f);
    }
    for (int i = lane; i < NH; i += 64) {
        v2f gx = Sx[i], gy = Sy[i], gz = Sz[i];
        v2f g2 = vfma(gx, gx, vfma(gy, gy, gz * gz));
        v2f d2a[4];
        #pragma unroll
        for (int r = 0; r < 4; ++r)
            d2a[r] = vmax0(vfma(v2(nx[r]), gx, vfma(v2(ny[r]), gy,
                           vfma(v2(nz[r]), gz, g2 + v2(p2[r])))));
        if (MODE == 0) {
            bool take = true;
            if (SKIP) {
                v2f mn = vmin2(vmin2(d2a[0], d2a[1]), vmin2(d2a[2], d2a[3]));
                take = __any(fminf(mn.x, mn.y) < thr);
            }
            if (take) {
                v2f rr = Sw[i];
                float2 q = nrp[i];
                v2f nr = (v2f){q.x, q.y};
                #pragma unroll
                for (int r = 0; r < 4; ++r) {
                    v2f e2 = vexp2(d2a[r] * v2(cq));
                    v2f e22 = e2 * e2;
                    an[r] = vfma(e2, nr, an[r]);
                    v2f t_ = (e22 * e22) * rr;
                    s1[r] += t_;
                    s2[r] = vfma(t_, vsqrt(d2a[r]), s2[r]);
                }
            }
        } else if (MODE == 1) {
            v2f rr = Sw[i];
            float2 q = nrp[i];
            anall += (v2f){q.x, q.y};
            #pragma unroll
            for (int r = 0; r < 4; ++r) {
                v2f t_ = vexp2(d2a[r] * v2(c1)) * rr;
                s1[r] += t_;
                s2[r] = vfma(t_, vsqrt(d2a[r]), s2[r]);
            }
        } else {
            v2f rr = Sw[i];
            #pragma unroll
            for (int r = 0; r < 4; ++r)
                s2[r] = vfma(rr, vsqrt(d2a[r]), s2[r]);
        }
    }
    float S1[4], S2[4], AN[4], ana = anall.x + anall.y;
    #pragma unroll
    for (int r = 0; r < 4; ++r) {
        S1[r] = s1[r].x + s1[r].y;
        S2[r] = s2[r].x + s2[r].y;
        AN[r] = an[r].x + an[r].y;
    }
    #pragma unroll
    for (int o = 1; o < 64; o <<= 1) {
        #pragma unroll
        for (int r = 0; r < 4; ++r) {
            S2[r] += __shfl_xor(S2[r], o);
            if (MODE <= 1) S1[r] += __shfl_xor(S1[r], o);
            if (MODE == 0) AN[r] += __shfl_xor(AN[r], o);
        }
        if (MODE == 1) ana += __shfl_xor(ana, o);
    }
    float contrib = 0.0f;
    if (lane < 4) {
        const int idx = b * NPTS + own0 + lane;
        const float rl = ratioL[idx];
        contrib = rl * SEL4(S2, lane);
        if (MODE <= 1) {
            const float sl = FIRST ? 1.0f : satl[idx];
            const float nsl = fmaxf(fmaf(-rl, SEL4(S1, lane), sl), 0.0f);
            satl[idx] = nsl;
            const float den = (MODE == 0) ? SEL4(AN, lane) : ana;
            ratioL[idx] = nsl / (den + EPS_F);
        }
    }
    contrib += __shfl_xor(contrib, 1);
    contrib += __shfl_xor(contrib, 2);       // lanes 0..3 hold wave total
    __syncthreads();                          // staging reads done; reuse LDS
    float* scr = (float*)Sx;
    if (lane == 0) scr[wave] = contrib;
    __syncthreads();
    if (tid == 0)
        atomicAdd(costAcc, scr[0] + scr[1] + scr[2] + scr[3]);
}

__global__ void finalize(const float* __restrict__ costAcc, float* __restrict__ out) {
    out[0] = costAcc[0] * (1.0f / (float)NPTS);   // radius = 1
}

extern "C" void kernel_launch(void* const* d_in, const int* in_sizes, int n_in,
                              void* d_out, int out_size, void* d_ws, size_t ws_size,
                              hipStream_t stream) {
    const float* pred = (const float*)d_in[0];
    const float* gt   = (const float*)d_in[1];
    float* out = (float*)d_out;

    float* wsf    = (float*)d_ws;
    float* satl   = wsf;
    float* satr   = wsf + NB * NPTS;
    float* ratioL = wsf + 2 * NB * NPTS;
    float* ratioR = wsf + 3 * NB * NPTS;
    float* costAcc = wsf + 4 * NB * NPTS;
    float* pp     = wsf + 4 * NB * NPTS + 16;       // sorted pred copy
    float* gg     = pp + NB * NPTS * 3;             // sorted gt copy

    // c[j] = level_j * log2(e); c[j+1] = c[j]/4 exactly for j<=8
    const double LOG2E = 1.4426950408889634;
    float c[11];
    for (int k = 0; k < 10; ++k) c[k] = (float)(-pow(4.0, (double)(8 - k)) * LOG2E);
    c[10] = 0.0f;

    const int blocks = NB * (NPTS / 16);   // 2048 blocks, 5 resident/CU

    sort_points<<<NB, 512, 0, stream>>>(pred, gt, pp, gg);

    row_start<<<blocks, TPB, 0, stream>>>(pp, gg, ratioL, costAcc, c[0]);
    // j = 0
    col_pass<true, true><<<blocks, TPB, 0, stream>>>(pp, gg, ratioL, ratioR, satr, c[0]);
    row_finish<0, true, true><<<blocks, TPB, 0, stream>>>(pp, gg, satl, ratioL, ratioR,
                                                          satr, costAcc, c[0], c[1]);
    // j = 1..4: both phases skip-qualified (sorted -> coherent granules)
    for (int j = 1; j <= 4; ++j) {
        col_pass<false, true><<<blocks, TPB, 0, stream>>>(pp, gg, ratioL, ratioR, satr, c[j]);
        row_finish<0, false, true><<<blocks, TPB, 0, stream>>>(pp, gg, satl, ratioL, ratioR,
                                                               satr, costAcc, c[j], c[j + 1]);
    }
    // j = 5: col skips; row dense
    col_pass<false, true><<<blocks, TPB, 0, stream>>>(pp, gg, ratioL, ratioR, satr, c[5]);
    row_finish<0, false, false><<<blocks, TPB, 0, stream>>>(pp, gg, satl, ratioL, ratioR,
                                                            satr, costAcc, c[5], c[6]);
    // j = 6..8: dense
    for (int j = 6; j <= 8; ++j) {
        col_pass<false, false><<<blocks, TPB, 0, stream>>>(pp, gg, ratioL, ratioR, satr, c[j]);
        row_finish<0, false, false><<<blocks, TPB, 0, stream>>>(pp, gg, satl, ratioL, ratioR,
                                                                satr, costAcc, c[j], c[j + 1]);
    }
    col_pass<false, false><<<blocks, TPB, 0, stream>>>(pp, gg, ratioL, ratioR, satr, c[9]);
    row_finish<1, false, false><<<blocks, TPB, 0, stream>>>(pp, gg, satl, ratioL, ratioR,
                                                            satr, costAcc, c[9], 0.0f);
    col_last<<<NB, 256, 0, stream>>>(ratioL, ratioR, satr);
    row_finish<2, false, false><<<blocks, TPB, 0, stream>>>(pp, gg, satl, ratioL, ratioR,
                                                            satr, costAcc, 0.0f, 0.0f);
    finalize<<<1, 1, 0, stream>>>(costAcc, out);
}